// Round 1
// baseline (1091.319 us; speedup 1.0000x reference)
//
#include <hip/hip_runtime.h>
#include <stdint.h>

#define BB 16
#define NN 4096
#define DD 128
#define MM 1024
#define RADIUS2 0.04f

// ---------------------------------------------------------------------------
// Phase 1: farthest-point sampling. One block per graph, 1024 threads,
// 4 points per thread held in registers. Block-wide argmax via packed u64
// (float bits << 32 | ~index) so max-reduce gives first-max tie-break.
// ---------------------------------------------------------------------------
__global__ __launch_bounds__(1024) void fps_kernel(const float* __restrict__ pos,
                                                   int* __restrict__ idx_out) {
    const int b   = blockIdx.x;
    const int tid = threadIdx.x;
    __shared__ float pos_lds[NN * 3];
    __shared__ unsigned long long partials[16];
    __shared__ unsigned long long result;

    const float* pg = pos + (size_t)b * NN * 3;
    for (int k = tid; k < NN * 3; k += 1024) pos_lds[k] = pg[k];
    __syncthreads();

    float px[4], py[4], pz[4], dist[4];
#pragma unroll
    for (int j = 0; j < 4; ++j) {
        int n = tid + j * 1024;
        px[j]   = pos_lds[n * 3 + 0];
        py[j]   = pos_lds[n * 3 + 1];
        pz[j]   = pos_lds[n * 3 + 2];
        dist[j] = __builtin_inff();
    }

    int last = 0;
    const int wid  = tid >> 6;
    const int lane = tid & 63;

    for (int m = 0; m < MM; ++m) {
        if (tid == 0) idx_out[b * MM + m] = last;   // record BEFORE update (scan semantics)
        if (m == MM - 1) break;

        // broadcast read of the last-selected point
        float lx = pos_lds[last * 3 + 0];
        float ly = pos_lds[last * 3 + 1];
        float lz = pos_lds[last * 3 + 2];

        unsigned long long best = 0ull;
#pragma unroll
        for (int j = 0; j < 4; ++j) {
            float dx = px[j] - lx;
            float dy = py[j] - ly;
            float dz = pz[j] - lz;
            // bit-exact: separate roundings, no FMA contraction, ((x+y)+z) order
            float d = __fadd_rn(__fadd_rn(__fmul_rn(dx, dx), __fmul_rn(dy, dy)),
                                __fmul_rn(dz, dz));
            dist[j] = fminf(dist[j], d);
            unsigned long long key =
                ((unsigned long long)__float_as_uint(dist[j]) << 32) |
                (unsigned long long)(0xFFFFFFFFu - (unsigned)(tid + j * 1024));
            best = key > best ? key : best;
        }
        // wave-level max reduce (64 lanes)
#pragma unroll
        for (int s = 1; s < 64; s <<= 1) {
            unsigned long long o = __shfl_xor(best, s, 64);
            best = o > best ? o : best;
        }
        if (lane == 0) partials[wid] = best;
        __syncthreads();
        // cross-wave reduce over 16 partials, done by wave 0
        if (wid == 0) {
            unsigned long long k = (lane < 16) ? partials[lane] : 0ull;
#pragma unroll
            for (int s = 1; s < 16; s <<= 1) {
                unsigned long long o = __shfl_xor(k, s, 64);
                k = o > k ? o : k;
            }
            if (lane == 0) result = k;
        }
        __syncthreads();
        last = (int)(0xFFFFFFFFu - (unsigned)(result & 0xFFFFFFFFull));
    }
}

// ---------------------------------------------------------------------------
// Phase 2a: gather sampled_x (float4-vectorized). One thread = 4 floats.
// ---------------------------------------------------------------------------
__global__ void gather_x_kernel(const float* __restrict__ x,
                                const int* __restrict__ idx,
                                float* __restrict__ out) {
    int t = blockIdx.x * blockDim.x + threadIdx.x;      // [0, BB*MM*DD/4)
    if (t >= BB * MM * DD / 4) return;
    int row = t >> 5;               // DD/4 = 32 float4 per row
    int c4  = (t & 31) << 2;
    int b   = row >> 10;            // /MM
    int n   = idx[row];             // local index within graph
    const float4 v = *(const float4*)(x + ((size_t)(b * NN + n) * DD + c4));
    *(float4*)(out + (size_t)row * DD + c4) = v;
}

// ---------------------------------------------------------------------------
// Phase 2b: gather sampled_pos + write batch ids (as float).
// ---------------------------------------------------------------------------
__global__ void gather_pb_kernel(const float* __restrict__ pos,
                                 const int* __restrict__ idx,
                                 float* __restrict__ spos,
                                 float* __restrict__ sbatch) {
    int r = blockIdx.x * blockDim.x + threadIdx.x;
    if (r >= BB * MM) return;
    int b = r >> 10;
    int n = idx[r];
    const float* p = pos + (size_t)(b * NN + n) * 3;
    spos[r * 3 + 0] = p[0];
    spos[r * 3 + 1] = p[1];
    spos[r * 3 + 2] = p[2];
    sbatch[r] = (float)b;
}

// ---------------------------------------------------------------------------
// Phase 3: radius adjacency. One block per (b, i) row; 256 threads x 4 j each,
// float4 store. Bit-exact d2 (no FMA) so the <= 0.04 threshold matches ref.
// ---------------------------------------------------------------------------
__global__ void adj_kernel(const float* __restrict__ spos,
                           float* __restrict__ adj) {
    int row = blockIdx.x;           // b*MM + i
    int b   = row >> 10;
    int i   = row & (MM - 1);
    const float* pb = spos + (size_t)b * MM * 3;
    float xi = pb[i * 3 + 0];
    float yi = pb[i * 3 + 1];
    float zi = pb[i * 3 + 2];

    int j0 = threadIdx.x << 2;
    float4 r;
    float* o = adj + (size_t)row * MM;
#pragma unroll
    for (int k = 0; k < 4; ++k) {
        int j = j0 + k;
        float dx = xi - pb[j * 3 + 0];
        float dy = yi - pb[j * 3 + 1];
        float dz = zi - pb[j * 3 + 2];
        float d2 = __fadd_rn(__fadd_rn(__fmul_rn(dx, dx), __fmul_rn(dy, dy)),
                             __fmul_rn(dz, dz));
        float v = (d2 <= RADIUS2 && j != i) ? 1.0f : 0.0f;
        ((float*)&r)[k] = v;
    }
    *(float4*)(o + j0) = r;
}

// ---------------------------------------------------------------------------
extern "C" void kernel_launch(void* const* d_in, const int* in_sizes, int n_in,
                              void* d_out, int out_size, void* d_ws, size_t ws_size,
                              hipStream_t stream) {
    const float* x   = (const float*)d_in[0];
    const float* pos = (const float*)d_in[1];
    // d_in[2] (batch) not needed: graphs are equal-size and sorted.

    float* out    = (float*)d_out;
    int*   idx_ws = (int*)d_ws;                 // BB*MM ints = 64 KB scratch

    float* sx   = out;                          // [BB*MM, DD]
    float* spos = sx + (size_t)BB * MM * DD;    // [BB*MM, 3]
    float* sbat = spos + (size_t)BB * MM * 3;   // [BB*MM]
    float* adj  = sbat + (size_t)BB * MM;       // [BB, MM, MM]

    fps_kernel<<<BB, 1024, 0, stream>>>(pos, idx_ws);
    gather_x_kernel<<<(BB * MM * DD / 4 + 255) / 256, 256, 0, stream>>>(x, idx_ws, sx);
    gather_pb_kernel<<<(BB * MM + 255) / 256, 256, 0, stream>>>(pos, idx_ws, spos, sbat);
    adj_kernel<<<BB * MM, 256, 0, stream>>>(spos, adj);
}

// Round 2
// 822.561 us; speedup vs baseline: 1.3267x; 1.3267x over previous
//
#include <hip/hip_runtime.h>
#include <stdint.h>

#define BB 16
#define NN 4096
#define DD 128
#define MM 1024
#define RADIUS2 0.04f
#define TPB 512
#define PPT 8              // points per thread: 512*8 = 4096
#define NW  (TPB / 64)     // waves per block

typedef unsigned long long u64;
typedef unsigned int u32;
typedef unsigned int uint2v __attribute__((ext_vector_type(2)));

__device__ __forceinline__ u64 umax64(u64 a, u64 b) { return a > b ? a : b; }

// Butterfly level via DPP (VALU latency, no DS pipe). Pattern: max(own, partner).
template <int CTRL>
__device__ __forceinline__ u64 dpp_max(u64 v) {
    u32 lo = (u32)__builtin_amdgcn_update_dpp(0, (int)(u32)v,         CTRL, 0xF, 0xF, true);
    u32 hi = (u32)__builtin_amdgcn_update_dpp(0, (int)(u32)(v >> 32), CTRL, 0xF, 0xF, true);
    return umax64(v, ((u64)hi << 32) | lo);
}

// xor-16 within each 32-lane half: ds_swizzle BitMode (xor=16, and=0x1F) = 0x401F.
__device__ __forceinline__ u64 swz16_max(u64 v) {
    u32 lo = (u32)__builtin_amdgcn_ds_swizzle((int)(u32)v,         0x401F);
    u32 hi = (u32)__builtin_amdgcn_ds_swizzle((int)(u32)(v >> 32), 0x401F);
    return umax64(v, ((u64)hi << 32) | lo);
}

// xor-32: permlane32_swap gives each lane {own, partner-half} pair -> max.
__device__ __forceinline__ u64 swap32_max(u64 v) {
#if __has_builtin(__builtin_amdgcn_permlane32_swap)
    uint2v lo = __builtin_amdgcn_permlane32_swap((u32)v,         (u32)v,         false, false);
    uint2v hi = __builtin_amdgcn_permlane32_swap((u32)(v >> 32), (u32)(v >> 32), false, false);
    u64 a = ((u64)hi[0] << 32) | (u64)lo[0];
    u64 b = ((u64)hi[1] << 32) | (u64)lo[1];
    return umax64(a, b);
#else
    return umax64(v, __shfl_xor(v, 32, 64));
#endif
}

__device__ __forceinline__ u64 wave_max(u64 k) {
    k = dpp_max<0xB1>(k);    // quad_perm [1,0,3,2]  : xor 1
    k = dpp_max<0x4E>(k);    // quad_perm [2,3,0,1]  : xor 2
    k = dpp_max<0x141>(k);   // row_half_mirror      : xor 7  -> groups of 8
    k = dpp_max<0x140>(k);   // row_mirror           : xor 15 -> groups of 16
    k = swz16_max(k);        // xor 16               -> groups of 32
    k = swap32_max(k);       // xor 32               -> full wave
    return k;
}

// ---------------------------------------------------------------------------
// FPS: one block (8 waves) per graph. Each thread owns 8 contiguous points in
// registers. Per iteration: 1 DPP/swizzle wave-argmax + 1 barrier + redundant
// cross-wave fold (everyone reads 8 partials -> no 2nd barrier/broadcast).
// Keys: (float_bits(dist) << 32) | (0xFFFFFFFF - idx) so u64-max = argmax with
// lowest-index tie-break, matching jnp.argmax.
// ---------------------------------------------------------------------------
__global__ __launch_bounds__(TPB) void fps_kernel(const float* __restrict__ pos,
                                                  int* __restrict__ idx_out) {
    const int b    = blockIdx.x;
    const int tid  = threadIdx.x;
    const int wid  = tid >> 6;
    const int lane = tid & 63;

    __shared__ float4 pos4[NN];            // padded xyz_ for 1x ds_read_b128 broadcast
    __shared__ u64 partials[2][NW];        // double-buffered: single barrier per iter

    const float* pg = pos + (size_t)b * NN * 3;
    for (int k = tid; k < NN * 3; k += TPB)
        ((float*)&pos4[k / 3])[k % 3] = pg[k];
    __syncthreads();

    float px[PPT], py[PPT], pz[PPT], dist[PPT];
#pragma unroll
    for (int j = 0; j < PPT; ++j) {
        float4 p = pos4[tid * PPT + j];
        px[j] = p.x; py[j] = p.y; pz[j] = p.z;
        dist[j] = __builtin_inff();
    }

    const u32 idx_base = 0xFFFFFFFFu - (u32)(tid * PPT);
    int last = 0;

    for (int m = 0; m < MM; ++m) {
        if (tid == 0) idx_out[b * MM + m] = last;   // record BEFORE update (scan semantics)
        if (m == MM - 1) break;

        float4 lp = pos4[last];                     // broadcast b128 read
        float lx = lp.x, ly = lp.y, lz = lp.z;

        u64 k[PPT];
#pragma unroll
        for (int j = 0; j < PPT; ++j) {
            float dx = px[j] - lx;
            float dy = py[j] - ly;
            float dz = pz[j] - lz;
            // bit-exact vs reference: separate roundings, no FMA, ((x2+y2)+z2)
            float d = __fadd_rn(__fadd_rn(__fmul_rn(dx, dx), __fmul_rn(dy, dy)),
                                __fmul_rn(dz, dz));
            dist[j] = fminf(dist[j], d);
            k[j] = ((u64)__float_as_uint(dist[j]) << 32) | (u64)(idx_base - (u32)j);
        }
#pragma unroll
        for (int s = PPT / 2; s > 0; s >>= 1)
#pragma unroll
            for (int j = 0; j < s; ++j) k[j] = umax64(k[j], k[j + s]);

        u64 key = wave_max(k[0]);

        const int buf = m & 1;
        if (lane == 0) partials[buf][wid] = key;
        __syncthreads();

        u64 t0[NW];
#pragma unroll
        for (int w = 0; w < NW; ++w) t0[w] = partials[buf][w];   // broadcast reads
#pragma unroll
        for (int s = NW / 2; s > 0; s >>= 1)
#pragma unroll
            for (int w = 0; w < s; ++w) t0[w] = umax64(t0[w], t0[w + s]);

        last = (int)(0xFFFFFFFFu - (u32)(t0[0] & 0xFFFFFFFFull));
    }
}

// ---------------------------------------------------------------------------
// Phase 2a: gather sampled_x (float4-vectorized).
// ---------------------------------------------------------------------------
__global__ void gather_x_kernel(const float* __restrict__ x,
                                const int* __restrict__ idx,
                                float* __restrict__ out) {
    int t = blockIdx.x * blockDim.x + threadIdx.x;
    if (t >= BB * MM * DD / 4) return;
    int row = t >> 5;               // DD/4 = 32 float4 per row
    int c4  = (t & 31) << 2;
    int b   = row >> 10;
    int n   = idx[row];
    const float4 v = *(const float4*)(x + ((size_t)(b * NN + n) * DD + c4));
    *(float4*)(out + (size_t)row * DD + c4) = v;
}

// ---------------------------------------------------------------------------
// Phase 2b: gather sampled_pos + batch ids (as float).
// ---------------------------------------------------------------------------
__global__ void gather_pb_kernel(const float* __restrict__ pos,
                                 const int* __restrict__ idx,
                                 float* __restrict__ spos,
                                 float* __restrict__ sbatch) {
    int r = blockIdx.x * blockDim.x + threadIdx.x;
    if (r >= BB * MM) return;
    int b = r >> 10;
    int n = idx[r];
    const float* p = pos + (size_t)(b * NN + n) * 3;
    spos[r * 3 + 0] = p[0];
    spos[r * 3 + 1] = p[1];
    spos[r * 3 + 2] = p[2];
    sbatch[r] = (float)b;
}

// ---------------------------------------------------------------------------
// Phase 3: radius adjacency, bit-exact d2 (no FMA).
// ---------------------------------------------------------------------------
__global__ void adj_kernel(const float* __restrict__ spos,
                           float* __restrict__ adj) {
    int row = blockIdx.x;           // b*MM + i
    int b   = row >> 10;
    int i   = row & (MM - 1);
    const float* pb = spos + (size_t)b * MM * 3;
    float xi = pb[i * 3 + 0];
    float yi = pb[i * 3 + 1];
    float zi = pb[i * 3 + 2];

    int j0 = threadIdx.x << 2;
    float4 r;
    float* o = adj + (size_t)row * MM;
#pragma unroll
    for (int k = 0; k < 4; ++k) {
        int j = j0 + k;
        float dx = xi - pb[j * 3 + 0];
        float dy = yi - pb[j * 3 + 1];
        float dz = zi - pb[j * 3 + 2];
        float d2 = __fadd_rn(__fadd_rn(__fmul_rn(dx, dx), __fmul_rn(dy, dy)),
                             __fmul_rn(dz, dz));
        float v = (d2 <= RADIUS2 && j != i) ? 1.0f : 0.0f;
        ((float*)&r)[k] = v;
    }
    *(float4*)(o + j0) = r;
}

// ---------------------------------------------------------------------------
extern "C" void kernel_launch(void* const* d_in, const int* in_sizes, int n_in,
                              void* d_out, int out_size, void* d_ws, size_t ws_size,
                              hipStream_t stream) {
    const float* x   = (const float*)d_in[0];
    const float* pos = (const float*)d_in[1];

    float* out    = (float*)d_out;
    int*   idx_ws = (int*)d_ws;                 // BB*MM ints = 64 KB scratch

    float* sx   = out;                          // [BB*MM, DD]
    float* spos = sx + (size_t)BB * MM * DD;    // [BB*MM, 3]
    float* sbat = spos + (size_t)BB * MM * 3;   // [BB*MM]
    float* adj  = sbat + (size_t)BB * MM;       // [BB, MM, MM]

    fps_kernel<<<BB, TPB, 0, stream>>>(pos, idx_ws);
    gather_x_kernel<<<(BB * MM * DD / 4 + 255) / 256, 256, 0, stream>>>(x, idx_ws, sx);
    gather_pb_kernel<<<(BB * MM + 255) / 256, 256, 0, stream>>>(pos, idx_ws, spos, sbat);
    adj_kernel<<<BB * MM, 256, 0, stream>>>(spos, adj);
}

// Round 3
// 690.036 us; speedup vs baseline: 1.5815x; 1.1921x over previous
//
#include <hip/hip_runtime.h>
#include <stdint.h>

#define BB 16
#define NN 4096
#define DD 128
#define MM 1024
#define RADIUS2 0.04f
#define TPB 256
#define PPT 16             // points per thread: 256*16 = 4096
#define NPAIR (PPT / 2)
#define NW  (TPB / 64)     // 4 waves

typedef unsigned long long u64;
typedef unsigned int u32;
typedef float f32x2 __attribute__((ext_vector_type(2)));
typedef unsigned int uint2v __attribute__((ext_vector_type(2)));

__device__ __forceinline__ u32 umin2(u32 a, u32 b) { return a < b ? a : b; }
__device__ __forceinline__ u32 umin3(u32 a, u32 b, u32 c) { return umin2(umin2(a, b), c); }  // -> v_min3_u32
__device__ __forceinline__ float fmax3(float a, float b, float c) { return fmaxf(fmaxf(a, b), c); } // -> v_max3_f32

// ---- wave-wide f32 max (all lanes get result): 4 DPP levels + swizzle16 + permlane32
template <int CTRL>
__device__ __forceinline__ float dpp_fmax(float v) {
    int o = __builtin_amdgcn_update_dpp(0, __float_as_int(v), CTRL, 0xF, 0xF, true);
    return fmaxf(v, __int_as_float(o));
}
__device__ __forceinline__ float wave_fmax(float v) {
    v = dpp_fmax<0xB1>(v);     // quad_perm xor1
    v = dpp_fmax<0x4E>(v);     // quad_perm xor2
    v = dpp_fmax<0x141>(v);    // row_half_mirror (xor within 8)
    v = dpp_fmax<0x140>(v);    // row_mirror (xor within 16)
    { int o = __builtin_amdgcn_ds_swizzle(__float_as_int(v), 0x401F); v = fmaxf(v, __int_as_float(o)); }
#if __has_builtin(__builtin_amdgcn_permlane32_swap)
    { uint2v r = __builtin_amdgcn_permlane32_swap(__float_as_uint(v), __float_as_uint(v), false, false);
      v = fmaxf(__uint_as_float(r[0]), __uint_as_float(r[1])); }
#else
    v = fmaxf(v, __shfl_xor(v, 32, 64));
#endif
    return v;
}
// ---- wave-wide u32 min
template <int CTRL>
__device__ __forceinline__ u32 dpp_umin(u32 v) {
    u32 o = (u32)__builtin_amdgcn_update_dpp(0, (int)v, CTRL, 0xF, 0xF, true);
    // bound_ctrl=true gives 0 for invalid lanes, but all butterfly sources are valid (all 64 lanes active)
    return umin2(v, o);
}
__device__ __forceinline__ u32 wave_umin(u32 v) {
    v = dpp_umin<0xB1>(v);
    v = dpp_umin<0x4E>(v);
    v = dpp_umin<0x141>(v);
    v = dpp_umin<0x140>(v);
    { u32 o = (u32)__builtin_amdgcn_ds_swizzle((int)v, 0x401F); v = umin2(v, o); }
#if __has_builtin(__builtin_amdgcn_permlane32_swap)
    { uint2v r = __builtin_amdgcn_permlane32_swap(v, v, false, false); v = umin2(r[0], r[1]); }
#else
    v = umin2(v, __shfl_xor(v, 32, 64));
#endif
    return v;
}

// ---------------------------------------------------------------------------
// FPS: one block (4 waves, 1 wave/SIMD -> no issue contention) per graph.
// Two-stage argmax: f32 wave-max -> equality scan -> u32 wave-min index.
// Cross-wave: lane0 writes {max_bits, idx} u64; lowest wave wins ties
// (waves own ascending disjoint index ranges -> matches jnp.argmax).
// ---------------------------------------------------------------------------
__global__ __launch_bounds__(TPB) void fps_kernel(const float* __restrict__ pos,
                                                  int* __restrict__ idx_out) {
    const int b    = blockIdx.x;
    const int tid  = threadIdx.x;
    const int wid  = tid >> 6;
    const int lane = tid & 63;

    __shared__ float4 pos4[NN];            // xyz_ padded for 1x b128 broadcast read
    __shared__ u64 partials[2][NW];        // double-buffered: single barrier per iter

    const float* pg = pos + (size_t)b * NN * 3;
    for (int k = tid; k < NN * 3; k += TPB)
        ((float*)&pos4[k / 3])[k % 3] = pg[k];
    __syncthreads();

    // thread owns points [tid*16, tid*16+16): px/py/pz packed as float2 pairs
    f32x2 px[NPAIR], py[NPAIR], pz[NPAIR];
    float dist[PPT];
    u32 idxs[PPT];
#pragma unroll
    for (int j = 0; j < NPAIR; ++j) {
        float4 a = pos4[tid * PPT + 2 * j];
        float4 c = pos4[tid * PPT + 2 * j + 1];
        px[j] = (f32x2){a.x, c.x};
        py[j] = (f32x2){a.y, c.y};
        pz[j] = (f32x2){a.z, c.z};
    }
#pragma unroll
    for (int k = 0; k < PPT; ++k) {
        dist[k] = __builtin_inff();
        idxs[k] = (u32)(tid * PPT + k);
    }

    int last = 0;

    for (int m = 0; m < MM; ++m) {
        if (tid == 0) idx_out[b * MM + m] = last;   // record BEFORE update (scan semantics)
        if (m == MM - 1) break;

        float4 lp = pos4[last];                     // broadcast b128 read
        f32x2 lx = {lp.x, lp.x}, ly = {lp.y, lp.y}, lz = {lp.z, lp.z};

        // distance update: packed f32 pairs, contraction OFF -> bit-exact
        // separate roundings ((dx2+dy2)+dz2), same bits as reference
        {
#pragma clang fp contract(off)
#pragma unroll
            for (int j = 0; j < NPAIR; ++j) {
                f32x2 dx = px[j] - lx;
                f32x2 dy = py[j] - ly;
                f32x2 dz = pz[j] - lz;
                f32x2 d  = dx * dx + dy * dy;
                d = d + dz * dz;
                dist[2 * j]     = fminf(dist[2 * j],     d.x);
                dist[2 * j + 1] = fminf(dist[2 * j + 1], d.y);
            }
        }

        // thread fold: max of 16 via max3 tree
        float t0 = fmax3(dist[0],  dist[1],  dist[2]);
        float t1 = fmax3(dist[3],  dist[4],  dist[5]);
        float t2 = fmax3(dist[6],  dist[7],  dist[8]);
        float t3 = fmax3(dist[9],  dist[10], dist[11]);
        float t4 = fmax3(dist[12], dist[13], dist[14]);
        float tmax = fmax3(fmax3(t0, t1, t2), fmaxf(t3, t4), dist[15]);

        float wmax = wave_fmax(tmax);

        // equality scan: lowest owned index whose dist == wmax (bit-exact move)
        u32 c[PPT];
#pragma unroll
        for (int k = 0; k < PPT; ++k)
            c[k] = (dist[k] == wmax) ? idxs[k] : 0xFFFFFFFFu;
        u32 s0 = umin3(c[0],  c[1],  c[2]);
        u32 s1 = umin3(c[3],  c[4],  c[5]);
        u32 s2 = umin3(c[6],  c[7],  c[8]);
        u32 s3 = umin3(c[9],  c[10], c[11]);
        u32 s4 = umin3(c[12], c[13], c[14]);
        u32 cand = umin3(umin3(s0, s1, s2), umin2(s3, s4), c[15]);

        u32 widx = wave_umin(cand);

        const int buf = m & 1;
        if (lane == 0)
            partials[buf][wid] = ((u64)__float_as_uint(wmax) << 32) | (u64)widx;
        __syncthreads();

        u64 e0 = partials[buf][0];
        u64 e1 = partials[buf][1];
        u64 e2 = partials[buf][2];
        u64 e3 = partials[buf][3];
        float m0 = __uint_as_float((u32)(e0 >> 32));
        float m1 = __uint_as_float((u32)(e1 >> 32));
        float m2 = __uint_as_float((u32)(e2 >> 32));
        float m3 = __uint_as_float((u32)(e3 >> 32));
        float g  = fmaxf(fmaxf(m0, m1), fmaxf(m2, m3));
        // lowest wave wins ties: select descending so wave 0 has priority
        u32 li = (u32)e3;
        li = (m2 == g) ? (u32)e2 : li;
        li = (m1 == g) ? (u32)e1 : li;
        li = (m0 == g) ? (u32)e0 : li;
        last = (int)li;
    }
}

// ---------------------------------------------------------------------------
// Phase 2a: gather sampled_x (float4-vectorized).
// ---------------------------------------------------------------------------
__global__ void gather_x_kernel(const float* __restrict__ x,
                                const int* __restrict__ idx,
                                float* __restrict__ out) {
    int t = blockIdx.x * blockDim.x + threadIdx.x;
    if (t >= BB * MM * DD / 4) return;
    int row = t >> 5;               // DD/4 = 32 float4 per row
    int c4  = (t & 31) << 2;
    int b   = row >> 10;
    int n   = idx[row];
    const float4 v = *(const float4*)(x + ((size_t)(b * NN + n) * DD + c4));
    *(float4*)(out + (size_t)row * DD + c4) = v;
}

// ---------------------------------------------------------------------------
// Phase 2b: gather sampled_pos + batch ids (as float).
// ---------------------------------------------------------------------------
__global__ void gather_pb_kernel(const float* __restrict__ pos,
                                 const int* __restrict__ idx,
                                 float* __restrict__ spos,
                                 float* __restrict__ sbatch) {
    int r = blockIdx.x * blockDim.x + threadIdx.x;
    if (r >= BB * MM) return;
    int b = r >> 10;
    int n = idx[r];
    const float* p = pos + (size_t)(b * NN + n) * 3;
    spos[r * 3 + 0] = p[0];
    spos[r * 3 + 1] = p[1];
    spos[r * 3 + 2] = p[2];
    sbatch[r] = (float)b;
}

// ---------------------------------------------------------------------------
// Phase 3: radius adjacency, bit-exact d2 (no FMA).
// ---------------------------------------------------------------------------
__global__ void adj_kernel(const float* __restrict__ spos,
                           float* __restrict__ adj) {
    int row = blockIdx.x;           // b*MM + i
    int b   = row >> 10;
    int i   = row & (MM - 1);
    const float* pb = spos + (size_t)b * MM * 3;
    float xi = pb[i * 3 + 0];
    float yi = pb[i * 3 + 1];
    float zi = pb[i * 3 + 2];

    int j0 = threadIdx.x << 2;
    float4 r;
    float* o = adj + (size_t)row * MM;
#pragma unroll
    for (int k = 0; k < 4; ++k) {
        int j = j0 + k;
        float dx = xi - pb[j * 3 + 0];
        float dy = yi - pb[j * 3 + 1];
        float dz = zi - pb[j * 3 + 2];
        float d2 = __fadd_rn(__fadd_rn(__fmul_rn(dx, dx), __fmul_rn(dy, dy)),
                             __fmul_rn(dz, dz));
        float v = (d2 <= RADIUS2 && j != i) ? 1.0f : 0.0f;
        ((float*)&r)[k] = v;
    }
    *(float4*)(o + j0) = r;
}

// ---------------------------------------------------------------------------
extern "C" void kernel_launch(void* const* d_in, const int* in_sizes, int n_in,
                              void* d_out, int out_size, void* d_ws, size_t ws_size,
                              hipStream_t stream) {
    const float* x   = (const float*)d_in[0];
    const float* pos = (const float*)d_in[1];

    float* out    = (float*)d_out;
    int*   idx_ws = (int*)d_ws;                 // BB*MM ints = 64 KB scratch

    float* sx   = out;                          // [BB*MM, DD]
    float* spos = sx + (size_t)BB * MM * DD;    // [BB*MM, 3]
    float* sbat = spos + (size_t)BB * MM * 3;   // [BB*MM]
    float* adj  = sbat + (size_t)BB * MM;       // [BB, MM, MM]

    fps_kernel<<<BB, TPB, 0, stream>>>(pos, idx_ws);
    gather_x_kernel<<<(BB * MM * DD / 4 + 255) / 256, 256, 0, stream>>>(x, idx_ws, sx);
    gather_pb_kernel<<<(BB * MM + 255) / 256, 256, 0, stream>>>(pos, idx_ws, spos, sbat);
    adj_kernel<<<BB * MM, 256, 0, stream>>>(spos, adj);
}